// Round 19
// baseline (84.371 us; speedup 1.0000x reference)
//
#include <hip/hip_runtime.h>
#include <cstdint>

namespace {

typedef _Float16 half2v __attribute__((ext_vector_type(2)));
typedef _Float16 half8 __attribute__((ext_vector_type(8)));
typedef float f32x4 __attribute__((ext_vector_type(4)));
typedef unsigned int u32x4 __attribute__((ext_vector_type(4)));

constexpr int KFS = 51;
constexpr int NB = 2, NC = 3, HH = 512, WW = 512;
constexpr int HP = HH + KFS - 1;   // 562
constexpr int WP = WW + KFS - 1;   // 562
constexpr size_t VSTR = (size_t)HH * WW;

constexpr int XCH = 32;              // output cols per block
constexpr int YR = 8;                // output rows per block (1 per wave)
constexpr int NTHREADS = 512;        // 8 waves
constexpr int NROWS = YR + 64 - 1;   // 71 staged in1 rows
constexpr int AFP = NROWS * 4;       // dw per (c,ks,lq) A plane (284)
constexpr int ASZ = NC * 3 * 4 * AFP;  // 10224 dw (40.9 KB)
constexpr int AV = NC * 3 * 4 * NROWS; // 2556 v-units
constexpr int SS = 26;               // f16-pair slots per (y,n)
constexpr int SLROW = SS + 2;        // 28: zero guards at slot 0 and 27
constexpr int SLSZ = YR * SLROW * 32;  // 7168 dw (28.7 KB)

__device__ __forceinline__ uint32_t pack2(float a, float b) {
  half2v p;
  p.x = (_Float16)a;  // RNE
  p.y = (_Float16)b;
  return __builtin_bit_cast(uint32_t, p);
}

// launch_bounds arg2: empirically cap = 512/(2*N) for 512-thread blocks
// ((512,4)->64 R14-16, (512,2)->128 R18). N=3 -> cap ~85: full prologue
// batching fits, 2 blocks/CU residency keeps margin below the VGPR pool.
__global__ __launch_bounds__(NTHREADS, 3)
void sepconv_mfma(const float* __restrict__ in1, const float* __restrict__ in2,
                  const float* __restrict__ in3, float* __restrict__ out) {
  __shared__ __align__(16) uint32_t ALDS[ASZ];  // A[c][ks][lq][row][4dw]
  __shared__ uint32_t SLAB[SLSZ];               // per-wave h-pair rows

  const int t = threadIdx.x;
  const int lane = t & 63;
  const int w = t >> 6;      // wave id == row offset within tile
  const int l15 = lane & 15;
  const int lq = lane >> 4;  // k-group (0..3)

  const int x0 = blockIdx.x * XCH;
  const int y0 = blockIdx.y * YR;
  const int b = blockIdx.z;

  const float* in1b = in1 + (size_t)b * NC * HP * WP;
  const float* v2 = in2 + (size_t)b * KFS * VSTR;
  const float* h3 = in3 + (size_t)b * KFS * VSTR;
  const int y = y0 + w;

  // ---- issue wave-local slab loads (26, into regs) -------------------------
  uint32_t* SLW = &SLAB[w * SLROW * 32];
  const int sn = lane & 31;
  const int shf = lane >> 5;  // 0 or 1
  float sa[13], sb[13];
  {
    const float* hp = h3 + (size_t)y * WW + x0 + sn;
    #pragma unroll
    for (int i = 0; i < 13; ++i) {
      const int s = 2 * i + shf;                 // s = 0..25, each once
      sa[i] = hp[(size_t)(2 * s) * VSTR];
      sb[i] = (2 * s + 1 < KFS) ? hp[(size_t)(2 * s + 1) * VSTR] : 0.f;
    }
  }

  // ---- A stage: 2 batches of 10 (issue-all, then write-all) ----------------
  const int e2 = t & 3;
  {
    int v = t >> 2;
    int ww2 = (v >= NROWS) ? 1 : 0;
    int r = v - ww2 * NROWS;
    float2 ga[10];
    #pragma unroll
    for (int half = 0; half < 2; ++half) {
      #pragma unroll
      for (int s = 0; s < 10; ++s) {
        float2 g = make_float2(0.f, 0.f);
        if (v < AV) {
          const int lqi = ww2 & 3;
          const int cks = ww2 >> 2;              // 0..8
          const int c = cks / 3;
          const int ks = cks - 3 * c;
          const int k0 = ks * 32 + lqi * 8 + 2 * e2;
          const int row = min(y0 + r, HP - 1);   // clamped rows weight-zeroed
          if (k0 < 82)
            g = *reinterpret_cast<const float2*>(
                in1b + ((size_t)c * HP + row) * WP + x0 + k0);
        }
        ga[s] = g;
        v += 128; r += 57; ww2 += 1;
        if (r >= NROWS) { r -= NROWS; ++ww2; }
      }
      #pragma unroll
      for (int s = 0; s < 10; ++s) {
        const int vv = (t >> 2) + 128 * (half * 10 + s);
        if (vv < AV) ALDS[(vv << 2) | e2] = pack2(ga[s].x, ga[s].y);
      }
    }
  }

  // ---- write slab (guards + data) ------------------------------------------
  SLW[(shf ? (SLROW - 1) : 0) * 32 + sn] = 0u;   // zero guard slots 0 and 27
  #pragma unroll
  for (int i = 0; i < 13; ++i) {
    const int s = 2 * i + shf;
    SLW[(s + 1) * 32 + sn] = pack2(sa[i], sb[i]);
  }
  __syncthreads();

  // ---- B fragments in registers (guard slots kill the zero-selects) --------
  const uint32_t* SLy = SLW;
  const int sh = (l15 & 1) * 16;
  u32x4 bf[2][3];
  #pragma unroll
  for (int nt = 0; nt < 2; ++nt) {
    const int n = nt * 16 + l15;
    #pragma unroll
    for (int ks = 0; ks < 3; ++ks) {
      const int j0 = ks * 32 + lq * 8 - n;
      const int sB = j0 >> 1;
      uint32_t P[5];
      #pragma unroll
      for (int u = 0; u < 5; ++u) {
        const int sc = min(max(sB + u, -1), SS) + 1;  // 0..27; 0 & 27 are zeros
        P[u] = SLy[sc * 32 + n];
      }
      u32x4 f;
      f.x = __builtin_amdgcn_alignbit(P[1], P[0], sh);
      f.y = __builtin_amdgcn_alignbit(P[2], P[1], sh);
      f.z = __builtin_amdgcn_alignbit(P[3], P[2], sh);
      f.w = __builtin_amdgcn_alignbit(P[4], P[3], sh);
      bf[nt][ks] = f;
    }
  }

  // ---- main MFMA loop; vw software-pipelined per-mt (16 live regs) ---------
  float vwc[2][4];
  #pragma unroll
  for (int nt = 0; nt < 2; ++nt)
    #pragma unroll
    for (int r = 0; r < 4; ++r) {
      const int m = lq * 4 + r;  // mt = 0
      vwc[nt][r] = (m < KFS)
          ? v2[(size_t)m * VSTR + (size_t)y * WW + x0 + nt * 16 + l15] : 0.f;
    }

  float ps[2][NC] = {};
  #pragma unroll
  for (int mt = 0; mt < 4; ++mt) {
    float vwn[2][4];
    if (mt < 3) {
      #pragma unroll
      for (int nt = 0; nt < 2; ++nt)
        #pragma unroll
        for (int r = 0; r < 4; ++r) {
          const int m = (mt + 1) * 16 + lq * 4 + r;
          vwn[nt][r] = (m < KFS)
              ? v2[(size_t)m * VSTR + (size_t)y * WW + x0 + nt * 16 + l15] : 0.f;
        }
    }
    #pragma unroll
    for (int c = 0; c < NC; ++c) {
      u32x4 af[3];
      #pragma unroll
      for (int ks = 0; ks < 3; ++ks)
        af[ks] = *reinterpret_cast<const u32x4*>(
            &ALDS[((c * 3 + ks) * 4 + lq) * AFP + (w + mt * 16 + l15) * 4]);
      #pragma unroll
      for (int nt = 0; nt < 2; ++nt) {
        f32x4 acc = {0.f, 0.f, 0.f, 0.f};
        #pragma unroll
        for (int ks = 0; ks < 3; ++ks)
          acc = __builtin_amdgcn_mfma_f32_16x16x32_f16(
              __builtin_bit_cast(half8, af[ks]),
              __builtin_bit_cast(half8, bf[nt][ks]), acc, 0, 0, 0);
        float p = acc[0] * vwc[nt][0];
        p = fmaf(acc[1], vwc[nt][1], p);
        p = fmaf(acc[2], vwc[nt][2], p);
        p = fmaf(acc[3], vwc[nt][3], p);
        ps[nt][c] += p;
      }
    }
    if (mt < 3) {
      #pragma unroll
      for (int nt = 0; nt < 2; ++nt)
        #pragma unroll
        for (int r = 0; r < 4; ++r) vwc[nt][r] = vwn[nt][r];
    }
  }

  // ---- wave-local m-reduce + merged 32-lane store ---------------------------
  #pragma unroll
  for (int c = 0; c < NC; ++c) {
    float pa = ps[0][c];
    pa += __shfl_xor(pa, 16);
    pa += __shfl_xor(pa, 32);
    float pb = ps[1][c];
    pb += __shfl_xor(pb, 16);
    pb += __shfl_xor(pb, 32);
    const float po = (lane < 16) ? pa : pb;
    if (lane < 32)
      out[((size_t)(b * NC + c) * HH + y) * WW + x0 + lane] = po;
  }
}

}  // namespace

extern "C" void kernel_launch(void* const* d_in, const int* in_sizes, int n_in,
                              void* d_out, int out_size, void* d_ws, size_t ws_size,
                              hipStream_t stream) {
  const float* in1 = (const float*)d_in[0];
  const float* in2 = (const float*)d_in[1];
  const float* in3 = (const float*)d_in[2];
  float* out = (float*)d_out;

  dim3 grid(WW / XCH, HH / YR, NB);
  sepconv_mfma<<<grid, NTHREADS, 0, stream>>>(in1, in2, in3, out);
}

// Round 20
// 73.162 us; speedup vs baseline: 1.1532x; 1.1532x over previous
//
#include <hip/hip_runtime.h>
#include <cstdint>

namespace {

typedef _Float16 half2v __attribute__((ext_vector_type(2)));
typedef _Float16 half8 __attribute__((ext_vector_type(8)));
typedef float f32x4 __attribute__((ext_vector_type(4)));
typedef unsigned int u32x4 __attribute__((ext_vector_type(4)));

constexpr int KFS = 51;
constexpr int NB = 2, NC = 3, HH = 512, WW = 512;
constexpr int HP = HH + KFS - 1;   // 562
constexpr int WP = WW + KFS - 1;   // 562
constexpr size_t VSTR = (size_t)HH * WW;

constexpr int XCH = 32;              // output cols per block
constexpr int YR = 8;                // output rows per block (1 per wave)
constexpr int NTHREADS = 512;        // 8 waves
constexpr int NROWS = YR + 64 - 1;   // 71 A slots (rows >=58 are zero-filled)
constexpr int NLOAD = 58;            // rows actually loaded (w + m <= 7 + 50)
constexpr int AFP = NROWS * 4;       // dw per (c,ks,lq) A plane (284)
constexpr int ASZ = NC * 3 * 4 * AFP;  // 10224 dw (40.9 KB)
constexpr int AV = NC * 3 * 4 * NROWS; // 2556 v-units
constexpr int SS = 26;               // f16-pair slots per (y,n)
constexpr int SLROW = SS + 2;        // 28: zero guards at slot 0 and 27
constexpr int SLSZ = YR * SLROW * 32;  // 7168 dw (28.7 KB)

__device__ __forceinline__ uint32_t pack2(float a, float b) {
  half2v p;
  p.x = (_Float16)a;  // RNE
  p.y = (_Float16)b;
  return __builtin_bit_cast(uint32_t, p);
}

// VGPR must stay <= 64: HW quantum jumps to 128 above 64 regs and only one
// 8-wave block then fits a CU (R18/R19 evidence). (512,4) pins the cap at 64.
__global__ __launch_bounds__(NTHREADS, 4)
void sepconv_mfma(const float* __restrict__ in1, const float* __restrict__ in2,
                  const float* __restrict__ in3, float* __restrict__ out) {
  __shared__ __align__(16) uint32_t ALDS[ASZ];  // A[c][ks][lq][row][4dw]
  __shared__ uint32_t SLAB[SLSZ];               // per-wave h-pair rows

  const int t = threadIdx.x;
  const int lane = t & 63;
  const int w = t >> 6;      // wave id == row offset within tile
  const int l15 = lane & 15;
  const int lq = lane >> 4;  // k-group (0..3)

  const int x0 = blockIdx.x * XCH;
  const int y0 = blockIdx.y * YR;
  const int b = blockIdx.z;

  const float* in1b = in1 + (size_t)b * NC * HP * WP;
  const float* v2 = in2 + (size_t)b * KFS * VSTR;
  const float* h3 = in3 + (size_t)b * KFS * VSTR;
  const int y = y0 + w;

  // ---- issue wave-local slab loads (26, into regs) -------------------------
  uint32_t* SLW = &SLAB[w * SLROW * 32];
  const int sn = lane & 31;
  const int shf = lane >> 5;  // 0 or 1
  float sa[13], sb[13];
  {
    const float* hp = h3 + (size_t)y * WW + x0 + sn;
    #pragma unroll
    for (int i = 0; i < 13; ++i) {
      const int s = 2 * i + shf;                 // s = 0..25, each once
      sa[i] = hp[(size_t)(2 * s) * VSTR];
      sb[i] = (2 * s + 1 < KFS) ? hp[(size_t)(2 * s + 1) * VSTR] : 0.f;
    }
  }

  // ---- A stage: 2 batches of 10 (issue-all, then write-all) ----------------
  // Rows r >= NLOAD only feed m >= 51 (vw == 0): write zeros, skip the load.
  const int e2 = t & 3;
  {
    int v = t >> 2;
    int ww2 = (v >= NROWS) ? 1 : 0;
    int r = v - ww2 * NROWS;
    float2 ga[10];
    #pragma unroll
    for (int half = 0; half < 2; ++half) {
      #pragma unroll
      for (int s = 0; s < 10; ++s) {
        float2 g = make_float2(0.f, 0.f);
        if (v < AV && r < NLOAD) {
          const int lqi = ww2 & 3;
          const int cks = ww2 >> 2;              // 0..8
          const int c = cks / 3;
          const int ks = cks - 3 * c;
          const int k0 = ks * 32 + lqi * 8 + 2 * e2;
          if (k0 < 82)                            // y0 + r <= 561 in-bounds
            g = *reinterpret_cast<const float2*>(
                in1b + ((size_t)c * HP + y0 + r) * WP + x0 + k0);
        }
        ga[s] = g;
        v += 128; r += 57; ww2 += 1;
        if (r >= NROWS) { r -= NROWS; ++ww2; }
      }
      #pragma unroll
      for (int s = 0; s < 10; ++s) {
        const int vv = (t >> 2) + 128 * (half * 10 + s);
        if (vv < AV) ALDS[(vv << 2) | e2] = pack2(ga[s].x, ga[s].y);
      }
    }
  }

  // ---- write slab (guards + data) ------------------------------------------
  SLW[(shf ? (SLROW - 1) : 0) * 32 + sn] = 0u;   // zero guard slots 0 and 27
  #pragma unroll
  for (int i = 0; i < 13; ++i) {
    const int s = 2 * i + shf;
    SLW[(s + 1) * 32 + sn] = pack2(sa[i], sb[i]);
  }
  __syncthreads();

  // ---- B fragments in registers (guard slots kill the zero-selects) --------
  const uint32_t* SLy = SLW;
  const int sh = (l15 & 1) * 16;
  u32x4 bf[2][3];
  #pragma unroll
  for (int nt = 0; nt < 2; ++nt) {
    const int n = nt * 16 + l15;
    #pragma unroll
    for (int ks = 0; ks < 3; ++ks) {
      const int j0 = ks * 32 + lq * 8 - n;
      const int sB = j0 >> 1;
      uint32_t P[5];
      #pragma unroll
      for (int u = 0; u < 5; ++u) {
        const int sc = min(max(sB + u, -1), SS) + 1;  // 0..27; 0 & 27 are zeros
        P[u] = SLy[sc * 32 + n];
      }
      u32x4 f;
      f.x = __builtin_amdgcn_alignbit(P[1], P[0], sh);
      f.y = __builtin_amdgcn_alignbit(P[2], P[1], sh);
      f.z = __builtin_amdgcn_alignbit(P[3], P[2], sh);
      f.w = __builtin_amdgcn_alignbit(P[4], P[3], sh);
      bf[nt][ks] = f;
    }
  }

  // ---- main MFMA loop; vw software-pipelined per-mt (16 live regs) ---------
  float vwc[2][4];
  #pragma unroll
  for (int nt = 0; nt < 2; ++nt)
    #pragma unroll
    for (int r = 0; r < 4; ++r) {
      const int m = lq * 4 + r;  // mt = 0
      vwc[nt][r] = (m < KFS)
          ? v2[(size_t)m * VSTR + (size_t)y * WW + x0 + nt * 16 + l15] : 0.f;
    }

  float ps[2][NC] = {};
  #pragma unroll
  for (int mt = 0; mt < 4; ++mt) {
    float vwn[2][4];
    if (mt < 3) {
      #pragma unroll
      for (int nt = 0; nt < 2; ++nt)
        #pragma unroll
        for (int r = 0; r < 4; ++r) {
          const int m = (mt + 1) * 16 + lq * 4 + r;
          vwn[nt][r] = (m < KFS)
              ? v2[(size_t)m * VSTR + (size_t)y * WW + x0 + nt * 16 + l15] : 0.f;
        }
    }
    #pragma unroll
    for (int c = 0; c < NC; ++c) {
      u32x4 af[3];
      #pragma unroll
      for (int ks = 0; ks < 3; ++ks)
        af[ks] = *reinterpret_cast<const u32x4*>(
            &ALDS[((c * 3 + ks) * 4 + lq) * AFP + (w + mt * 16 + l15) * 4]);
      #pragma unroll
      for (int nt = 0; nt < 2; ++nt) {
        f32x4 acc = {0.f, 0.f, 0.f, 0.f};
        #pragma unroll
        for (int ks = 0; ks < 3; ++ks)
          acc = __builtin_amdgcn_mfma_f32_16x16x32_f16(
              __builtin_bit_cast(half8, af[ks]),
              __builtin_bit_cast(half8, bf[nt][ks]), acc, 0, 0, 0);
        float p = acc[0] * vwc[nt][0];
        p = fmaf(acc[1], vwc[nt][1], p);
        p = fmaf(acc[2], vwc[nt][2], p);
        p = fmaf(acc[3], vwc[nt][3], p);
        ps[nt][c] += p;
      }
    }
    if (mt < 3) {
      #pragma unroll
      for (int nt = 0; nt < 2; ++nt)
        #pragma unroll
        for (int r = 0; r < 4; ++r) vwc[nt][r] = vwn[nt][r];
    }
  }

  // ---- wave-local m-reduce + merged 32-lane store ---------------------------
  #pragma unroll
  for (int c = 0; c < NC; ++c) {
    float pa = ps[0][c];
    pa += __shfl_xor(pa, 16);
    pa += __shfl_xor(pa, 32);
    float pb = ps[1][c];
    pb += __shfl_xor(pb, 16);
    pb += __shfl_xor(pb, 32);
    const float po = (lane < 16) ? pa : pb;
    if (lane < 32)
      out[((size_t)(b * NC + c) * HH + y) * WW + x0 + lane] = po;
  }
}

}  // namespace

extern "C" void kernel_launch(void* const* d_in, const int* in_sizes, int n_in,
                              void* d_out, int out_size, void* d_ws, size_t ws_size,
                              hipStream_t stream) {
  const float* in1 = (const float*)d_in[0];
  const float* in2 = (const float*)d_in[1];
  const float* in3 = (const float*)d_in[2];
  float* out = (float*)d_out;

  dim3 grid(WW / XCH, HH / YR, NB);
  sepconv_mfma<<<grid, NTHREADS, 0, stream>>>(in1, in2, in3, out);
}